// Round 12
// baseline (22.014 us; speedup 1.0000x reference)
//
#include <hip/hip_runtime.h>
#include <hip/hip_bf16.h>

#define NBATCH 512
#define NS 66
#define ND 304
#define NK 128
#define NTHREADS 640            // 10 waves: (M-tile 0..4) x (N-half 0..1)
#define NBLOCKS (NBATCH / 2)    // persistent: 2 batches per block, 1 block/CU

#define WSTRIDE_B 640                       // 320 bf16 per W row (k padded)
#define WLDS_BYTES (128 * WSTRIDE_B)        // 81920
#define TSTRIDE_B 256                       // 128 bf16 per t row
#define TBYTES (80 * TSTRIDE_B)             // 20480 per t buffer (x2)

typedef __attribute__((ext_vector_type(8))) short bf16x8;
typedef __attribute__((ext_vector_type(4))) short s16x4;
typedef __attribute__((ext_vector_type(4))) float f32x4;

__device__ __forceinline__ short f2bf(float x) {
    return __builtin_bit_cast(short, __float2bfloat16(x));
}

// 15 upper-triangle 16x16 tiles of G: 5 diagonal first, then 10 strict-upper.
__device__ const int TI_LUT[15] = {0,1,2,3,4, 0,0,0,0,1,1,1,2,2,3};
__device__ const int TJ_LUT[15] = {0,1,2,3,4, 1,2,3,4,2,3,4,3,4,4};

// raw barrier: waits this wave's LDS ops + all waves arrive; vmem stays in flight
#define LDS_BARRIER() asm volatile("s_waitcnt lgkmcnt(0)\n\ts_barrier" ::: "memory")

__global__ __launch_bounds__(NTHREADS, 2) void treeprobe_mfma(
    const float* __restrict__ x,   // [512][66][304]
    const float* __restrict__ W,   // [128][304]
    float* __restrict__ out)       // [512][66][66]
{
    __shared__ __align__(16) char w_lds[WLDS_BYTES];   // W bf16, swizzled
    __shared__ __align__(16) char t_lds[2 * TBYTES];   // t bf16, double-buffered
    __shared__ float norms[2][80];

    const int tid  = threadIdx.x;
    const int lane = tid & 63;
    const int wv   = tid >> 6;      // 0..9
    const int mt   = wv >> 1;       // M-tile 0..4 (16 s-rows)
    const int nh   = wv & 1;        // N-half (64 t-cols)
    const int lr   = lane & 15;
    const int lg   = lane >> 4;     // 0..3

    const int b0 = blockIdx.x * 2;
    const int xrow = mt * 16 + lr;                 // s row 0..79
    const bool rowok = xrow < NS;
    const float* __restrict__ xr0p = x + ((size_t)b0 * NS + xrow) * ND;
    const float* __restrict__ xr1p = xr0p + NS * ND;

    // issue x quad-pair for k-chunk kk of this lane's row into float4 d[2]
#define XQ(d, rp, kk) do {                                                    \
        const int k0_ = (kk) * 32 + lg * 8;                                   \
        if (rowok && k0_ < ND) {                                              \
            d[0] = *reinterpret_cast<const float4*>((rp) + k0_);              \
            d[1] = *reinterpret_cast<const float4*>((rp) + k0_ + 4);          \
        } else {                                                              \
            d[0] = make_float4(0.f, 0.f, 0.f, 0.f);                           \
            d[1] = make_float4(0.f, 0.f, 0.f, 0.f);                           \
        }                                                                     \
    } while (0)

#define CVT_B(bf, d) do {                                                     \
        bf[0] = f2bf(d[0].x); bf[1] = f2bf(d[0].y);                           \
        bf[2] = f2bf(d[0].z); bf[3] = f2bf(d[0].w);                           \
        bf[4] = f2bf(d[1].x); bf[5] = f2bf(d[1].y);                           \
        bf[6] = f2bf(d[1].z); bf[7] = f2bf(d[1].w);                           \
    } while (0)

    // ---- prologue issue order: x0 c0,c1 | all W | x0 c2..c9 ----
    // (in-order vmem retirement: W lands after only 4 x loads -> W-stage
    //  doesn't wait the x stream; x c2-9 stay in flight through phase 1)
    float4 xq[10][2];
    XQ(xq[0], xr0p, 0);
    XQ(xq[1], xr0p, 1);

    float4 wbuf[16];                // 9728 float4 of W over 640 threads
#pragma unroll
    for (int j = 0; j < 16; ++j) {
        const int e = tid + j * NTHREADS;
        wbuf[j] = (e < 9728)
            ? *reinterpret_cast<const float4*>(W + (e / 76) * ND + (e % 76) * 4)
            : make_float4(0.f, 0.f, 0.f, 0.f);
    }

#pragma unroll
    for (int kk = 2; kk < 10; ++kk) XQ(xq[kk], xr0p, kk);

    // zero k-pad slots 38,39 (k 304..319) for all 128 W rows
    for (int i = tid; i < 256; i += NTHREADS) {
        const int row = i >> 1;
        const int byte = (row * WSTRIDE_B + (38 + (i & 1)) * 16) ^ ((row & 7) << 4);
        *reinterpret_cast<f32x4*>(w_lds + byte) = (f32x4){0.f, 0.f, 0.f, 0.f};
    }

    // convert + write W -> LDS (counted vmcnt waits; x c2-9 remain in flight)
#pragma unroll
    for (int j = 0; j < 16; ++j) {
        const int e = tid + j * NTHREADS;
        if (e < 9728) {
            const int row = e / 76, q = e % 76;
            const int byte =
                ((row * WSTRIDE_B + (q >> 1) * 16) ^ ((row & 7) << 4)) | ((q & 1) << 3);
            s16x4 sv;
            sv[0] = f2bf(wbuf[j].x); sv[1] = f2bf(wbuf[j].y);
            sv[2] = f2bf(wbuf[j].z); sv[3] = f2bf(wbuf[j].w);
            *reinterpret_cast<s16x4*>(w_lds + byte) = sv;
        }
    }
    LDS_BARRIER();      // W visible; x stream in flight

    // ---- phase 1 (+ t-write): barrier-free, x from regs, W from LDS ----
#define PH1_TW(tb) do {                                                       \
        f32x4 acc[4];                                                         \
        acc[0] = (f32x4){0.f,0.f,0.f,0.f}; acc[1] = (f32x4){0.f,0.f,0.f,0.f}; \
        acc[2] = (f32x4){0.f,0.f,0.f,0.f}; acc[3] = (f32x4){0.f,0.f,0.f,0.f}; \
        _Pragma("unroll")                                                     \
        for (int kk = 0; kk < 10; ++kk) {                                     \
            bf16x8 bfr;                                                       \
            CVT_B(bfr, xq[kk]);                                               \
            _Pragma("unroll")                                                 \
            for (int nt = 0; nt < 4; ++nt) {                                  \
                const int wrow = nh * 64 + nt * 16 + lr;                      \
                const int byte =                                              \
                    (wrow * WSTRIDE_B + kk * 64 + lg * 16) ^ ((wrow & 7) << 4);\
                const bf16x8 wfr =                                            \
                    *reinterpret_cast<const bf16x8*>(w_lds + byte);           \
                acc[nt] = __builtin_amdgcn_mfma_f32_16x16x32_bf16(            \
                    wfr, bfr, acc[nt], 0, 0, 0);                              \
            }                                                                 \
        }                                                                     \
        /* t: D col(lr)=s(==xrow), row(lg*4+r)=c -> 8B packed */              \
        _Pragma("unroll")                                                     \
        for (int nt = 0; nt < 4; ++nt) {                                      \
            const int c0 = nh * 64 + nt * 16 + lg * 4;                        \
            const int byte = (xrow * TSTRIDE_B + c0 * 2) ^ ((xrow & 7) << 4); \
            s16x4 sv;                                                         \
            sv[0] = f2bf(acc[nt][0]); sv[1] = f2bf(acc[nt][1]);               \
            sv[2] = f2bf(acc[nt][2]); sv[3] = f2bf(acc[nt][3]);               \
            *reinterpret_cast<s16x4*>(t_lds + (tb) + byte) = sv;              \
        }                                                                     \
    } while (0)

    // ---- phase 2 + epilogue on buffer tb / norms nn ----
#define GRAM_OUT(tb, nn, obp) do {                                            \
        f32x4 g[2]; int ti[2], tj[2]; bool val[2], dia[2];                    \
        _Pragma("unroll")                                                     \
        for (int si = 0; si < 2; ++si) {                                      \
            const int pos = wv + si * 10;                                     \
            val[si] = pos < 15;                                               \
            g[si] = (f32x4){0.f,0.f,0.f,0.f};                                 \
            ti[si] = 0; tj[si] = 0; dia[si] = false;                          \
            if (val[si]) {                                                    \
                ti[si] = TI_LUT[pos]; tj[si] = TJ_LUT[pos];                   \
                dia[si] = pos < 5;                                            \
                _Pragma("unroll")                                             \
                for (int kk = 0; kk < 4; ++kk) {                              \
                    const int ra = ti[si] * 16 + lr;                          \
                    const int ba =                                            \
                        (ra * TSTRIDE_B + kk * 64 + lg * 16) ^ ((ra & 7) << 4);\
                    const int rb = tj[si] * 16 + lr;                          \
                    const int bb =                                            \
                        (rb * TSTRIDE_B + kk * 64 + lg * 16) ^ ((rb & 7) << 4);\
                    g[si] = __builtin_amdgcn_mfma_f32_16x16x32_bf16(          \
                        *reinterpret_cast<const bf16x8*>(t_lds + (tb) + ba),  \
                        *reinterpret_cast<const bf16x8*>(t_lds + (tb) + bb),  \
                        g[si], 0, 0, 0);                                      \
                }                                                             \
                if (dia[si]) {                                                \
                    _Pragma("unroll")                                         \
                    for (int r = 0; r < 4; ++r)                               \
                        if (lr == lg * 4 + r)                                 \
                            norms[nn][ti[si] * 16 + lr] = g[si][r];           \
                }                                                             \
            }                                                                 \
        }                                                                     \
        LDS_BARRIER();                                                        \
        _Pragma("unroll")                                                     \
        for (int si = 0; si < 2; ++si) {                                      \
            if (val[si]) {                                                    \
                const int j = tj[si] * 16 + lr;                               \
                const float nj = norms[nn][j];                                \
                float v[4];                                                   \
                _Pragma("unroll")                                             \
                for (int r = 0; r < 4; ++r) {                                 \
                    const int i_ = ti[si] * 16 + lg * 4 + r;                  \
                    v[r] = norms[nn][i_] + nj - 2.f * g[si][r];               \
                    if (i_ < NS && j < NS) (obp)[i_ * NS + j] = v[r];         \
                }                                                             \
                if (!dia[si] && j < NS) {                                     \
                    const int i0 = ti[si] * 16 + lg * 4;  /* ti<=3 -> <64 */  \
                    *reinterpret_cast<float2*>((obp) + j * NS + i0) =         \
                        make_float2(v[0], v[1]);                              \
                    *reinterpret_cast<float2*>((obp) + j * NS + i0 + 2) =     \
                        make_float2(v[2], v[3]);                              \
                }                                                             \
            }                                                                 \
        }                                                                     \
    } while (0)

    float* __restrict__ ob0 = out + (size_t)b0 * NS * NS;
    float* __restrict__ ob1 = ob0 + NS * NS;

    // ---- batch b0 phase 1 ----
    PH1_TW(0);

    // issue ALL of x(b1): streams under b0 ph2 + epilogue + b1 compute
#pragma unroll
    for (int kk = 0; kk < 10; ++kk) XQ(xq[kk], xr1p, kk);

    LDS_BARRIER();                  // t0 visible
    GRAM_OUT(0, 0, ob0);            // b0 Gram + out (internal barrier for norms)

    // ---- batch b1: t-buf1, no wait on b0 readers (double-buffered) ----
    PH1_TW(TBYTES);
    LDS_BARRIER();                  // t1 visible
    GRAM_OUT(TBYTES, 1, ob1);

#undef XQ
#undef CVT_B
#undef PH1_TW
#undef GRAM_OUT
}

extern "C" void kernel_launch(void* const* d_in, const int* in_sizes, int n_in,
                              void* d_out, int out_size, void* d_ws, size_t ws_size,
                              hipStream_t stream) {
    const float* x = (const float*)d_in[0];   // (512, 66, 304) f32
    const float* W = (const float*)d_in[1];   // (128, 304) f32
    // d_in[2] = b : cancels in the pairwise difference, unused.
    float* out = (float*)d_out;               // (512, 66, 66) f32

    treeprobe_mfma<<<NBLOCKS, NTHREADS, 0, stream>>>(x, W, out);
}